// Round 2
// baseline (460.524 us; speedup 1.0000x reference)
//
#include <hip/hip_runtime.h>

typedef __bf16 bf16;
typedef __bf16 bf16x8 __attribute__((ext_vector_type(8)));
typedef float  f32x4  __attribute__((ext_vector_type(4)));

#define S 512
#define DD 768
#define LL 64
#define BB 4

__device__ __forceinline__ void async_copy16(const void* g, void* l) {
    __builtin_amdgcn_global_load_lds(
        (const __attribute__((address_space(1))) unsigned int*)g,
        (__attribute__((address_space(3))) unsigned int*)l,
        16, 0, 0);
}

__device__ __forceinline__ bf16x8 scale_cvt(float4 a, float4 b, float4 ua, float4 ub) {
    bf16x8 p;
    p[0] = (bf16)(a.x * ua.x); p[1] = (bf16)(a.y * ua.y);
    p[2] = (bf16)(a.z * ua.z); p[3] = (bf16)(a.w * ua.w);
    p[4] = (bf16)(b.x * ub.x); p[5] = (bf16)(b.y * ub.y);
    p[6] = (bf16)(b.z * ub.z); p[7] = (bf16)(b.w * ub.w);
    return p;
}

// ---------------- prepass 1: dep fp32 -> bf16 ----------------
__global__ void cvt_dep_kernel(const float* __restrict__ dep, bf16* __restrict__ out) {
    int idx = (blockIdx.x * 256 + threadIdx.x) * 8;
    float4 a = *(const float4*)(dep + idx);
    float4 c = *(const float4*)(dep + idx + 4);
    bf16x8 p;
    p[0] = (bf16)a.x; p[1] = (bf16)a.y; p[2] = (bf16)a.z; p[3] = (bf16)a.w;
    p[4] = (bf16)c.x; p[5] = (bf16)c.y; p[6] = (bf16)c.z; p[7] = (bf16)c.w;
    *(bf16x8*)(out + idx) = p;
}

// ---------------- prepass 2: Ah[b,l,i,d] = bf16(head[b,i,d] * U[l,d]) ----------------
__global__ void scaleA_kernel(const float* __restrict__ head, const float* __restrict__ U,
                              bf16* __restrict__ out) {
    int l = blockIdx.y;
    int b = blockIdx.z;
    int e = blockIdx.x * 2048 + threadIdx.x * 8;      // within S*DD slice
    int d = e - (e / DD) * DD;                        // e % 768 (multiple of 8)
    const float* hp = head + (size_t)b * S * DD + e;
    const float* up = U + l * DD + d;
    float4 a  = *(const float4*)hp;
    float4 c  = *(const float4*)(hp + 4);
    float4 ua = *(const float4*)up;
    float4 ub = *(const float4*)(up + 4);
    *(bf16x8*)(out + (size_t)(b * LL + l) * S * DD + e) = scale_cvt(a, c, ua, ub);
}

// ---------------- prepass 3: t2h[b,l,i], t2d'[b,l,o] (+bias) ----------------
// grid 512: bid>>8 = sel; then b(4) x lgroup(4) x ichunk(16 x 32 rows)
__global__ void t2_kernel(const float* __restrict__ head, const float* __restrict__ dep,
                          const float* __restrict__ W, const float* __restrict__ bias,
                          float* __restrict__ t2h, float* __restrict__ t2d) {
    __shared__ float Wl[16][DD];
    __shared__ float red[32][8][16];
    int bid = blockIdx.x;
    int sel = bid >> 8;
    int r   = bid & 255;
    int b   = r >> 6;
    int lg  = (r >> 4) & 3;
    int ic  = r & 15;
    const float* src = sel ? dep : head;
    int t = threadIdx.x;

    // stage 16 W rows (float4, flat): 16*192 float4 over 256 threads = 12 each
#pragma unroll
    for (int k = 0; k < 12; ++k) {
        int idx = t + k * 256;
        int row = idx / 192;
        int col = idx - row * 192;
        const float* wp = W + (size_t)(lg * 16 + row) * (2 * DD) + sel * DD + col * 4;
        *(float4*)&Wl[row][col * 4] = *(const float4*)wp;
    }
    __syncthreads();

    int iq = t >> 3, dq = t & 7;                  // 32 rows x 8 d-slices
    int i  = ic * 32 + iq;
    const float* rowp = src + (size_t)(b * S + i) * DD;
    float acc[16];
#pragma unroll
    for (int l16 = 0; l16 < 16; ++l16) acc[l16] = 0.f;
    for (int it = 0; it < 24; ++it) {
        int d = dq * 4 + it * 32;
        float4 x = *(const float4*)(rowp + d);
#pragma unroll
        for (int l16 = 0; l16 < 16; ++l16) {
            float4 wv = *(const float4*)&Wl[l16][d];
            acc[l16] += x.x * wv.x + x.y * wv.y + x.z * wv.z + x.w * wv.w;
        }
    }
#pragma unroll
    for (int l16 = 0; l16 < 16; ++l16) red[iq][dq][l16] = acc[l16];
    __syncthreads();

    int iq2 = t >> 3, l2 = t & 7;
    float* dst = sel ? t2d : t2h;
#pragma unroll
    for (int j = 0; j < 2; ++j) {
        int l16 = l2 * 2 + j;
        float v = 0.f;
#pragma unroll
        for (int dq2 = 0; dq2 < 8; ++dq2) v += red[iq2][dq2][l16];
        if (sel) v += bias[lg * 16 + l16];
        dst[(size_t)(b * LL + lg * 16 + l16) * S + ic * 32 + iq2] = v;
    }
}

// ---------------- main: C[b,l] = Ah[b,l] @ depb[b]^T + epilogue ----------------
__global__ __launch_bounds__(256, 2) void biaffine_main(
    const bf16* __restrict__ Ah, const bf16* __restrict__ depb,
    const float* __restrict__ t2h, const float* __restrict__ t2d,
    float* __restrict__ out) {
    __shared__ __align__(16) bf16 As[128][32];
    __shared__ __align__(16) bf16 Bs[128][32];

    const int tid  = threadIdx.x;
    const int lane = tid & 63;
    const int w    = tid >> 6;
    const int bi0  = (blockIdx.x & 3) << 7;
    const int bo0  = (blockIdx.x >> 2) << 7;
    const int l    = blockIdx.y;
    const int b    = blockIdx.z;

    // staging: wave w fills rows [w*32, w*32+32) of both tiles, 2 async/tile
    const int rS  = w * 32 + (lane >> 2);         // and rS+16
    const int cpS = lane & 3;
    const int sw  = (rS >> 1) & 3;                // same for rS and rS+16
    const int ca  = cpS ^ sw;
    const bf16* Abase = Ah + (size_t)(b * LL + l) * S * DD;
    const bf16* ga0 = Abase + (size_t)(bi0 + rS) * DD + ca * 8;
    const bf16* ga1 = ga0 + (size_t)16 * DD;
    const bf16* gb0 = depb + (size_t)(b * S + bo0 + rS) * DD + ca * 8;
    const bf16* gb1 = gb0 + (size_t)16 * DD;
    bf16* lwa0 = &As[w * 32][0];
    bf16* lwa1 = &As[w * 32 + 16][0];
    bf16* lwb0 = &Bs[w * 32][0];
    bf16* lwb1 = &Bs[w * 32 + 16][0];

    // fragment pointers
    const int wr = w & 1, wc = w >> 1;
    const int mrow = lane & 15, q = lane >> 4;
    const bf16* ap[4];
    const bf16* bp[4];
#pragma unroll
    for (int mi = 0; mi < 4; ++mi) {
        int rowA = wr * 64 + mi * 16 + mrow;
        ap[mi] = &As[rowA][(q ^ ((rowA >> 1) & 3)) * 8];
        int rowB = wc * 64 + mi * 16 + mrow;
        bp[mi] = &Bs[rowB][(q ^ ((rowB >> 1) & 3)) * 8];
    }

    f32x4 acc[4][4];
#pragma unroll
    for (int mi = 0; mi < 4; ++mi)
#pragma unroll
        for (int ni = 0; ni < 4; ++ni)
            acc[mi][ni] = (f32x4){0.f, 0.f, 0.f, 0.f};

    for (int kt = 0; kt < 24; ++kt) {
        async_copy16(ga0, lwa0);
        async_copy16(ga1, lwa1);
        async_copy16(gb0, lwb0);
        async_copy16(gb1, lwb1);
        ga0 += 32; ga1 += 32; gb0 += 32; gb1 += 32;
        __syncthreads();

        bf16x8 af[4], bfr[4];
#pragma unroll
        for (int mi = 0; mi < 4; ++mi) af[mi]  = *(const bf16x8*)ap[mi];
#pragma unroll
        for (int ni = 0; ni < 4; ++ni) bfr[ni] = *(const bf16x8*)bp[ni];
#pragma unroll
        for (int mi = 0; mi < 4; ++mi)
#pragma unroll
            for (int ni = 0; ni < 4; ++ni)
                acc[mi][ni] = __builtin_amdgcn_mfma_f32_16x16x32_bf16(af[mi], bfr[ni], acc[mi][ni], 0, 0, 0);
        __syncthreads();
    }

    // epilogue: + t2h[row] + t2d'[col]
    const size_t bl = (size_t)(b * LL + l);
    const float* t2hp = t2h + bl * S + bi0 + wr * 64;
    const float* t2dp = t2d + bl * S + bo0 + wc * 64;
    float* outbase = out + bl * S * S;
#pragma unroll
    for (int mi = 0; mi < 4; ++mi) {
        float4 th = *(const float4*)&t2hp[mi * 16 + q * 4];
        int row0 = bi0 + wr * 64 + mi * 16 + q * 4;
#pragma unroll
        for (int ni = 0; ni < 4; ++ni) {
            int col = bo0 + wc * 64 + ni * 16 + mrow;
            float td = t2dp[ni * 16 + mrow];
            float* op = outbase + (size_t)row0 * S + col;
            op[0 * S] = acc[mi][ni][0] + th.x + td;
            op[1 * S] = acc[mi][ni][1] + th.y + td;
            op[2 * S] = acc[mi][ni][2] + th.z + td;
            op[3 * S] = acc[mi][ni][3] + th.w + td;
        }
    }
}

extern "C" void kernel_launch(void* const* d_in, const int* in_sizes, int n_in,
                              void* d_out, int out_size, void* d_ws, size_t ws_size,
                              hipStream_t stream) {
    const float* head = (const float*)d_in[0];
    const float* dep  = (const float*)d_in[1];
    const float* U    = (const float*)d_in[2];
    const float* W    = (const float*)d_in[3];
    const float* bias = (const float*)d_in[4];
    float* out = (float*)d_out;

    char*  ws   = (char*)d_ws;
    bf16*  Ahb  = (bf16*)ws;                                    // B*L*S*D*2 = 201,326,592 B
    bf16*  depb = (bf16*)(ws + 201326592);                      // B*S*D*2   =   3,145,728 B
    float* t2h  = (float*)(ws + 201326592 + 3145728);           // B*L*S*4   =     524,288 B
    float* t2d  = (float*)(ws + 201326592 + 3145728 + 524288);  // B*L*S*4   =     524,288 B

    cvt_dep_kernel<<<768, 256, 0, stream>>>(dep, depb);
    scaleA_kernel<<<dim3(192, LL, BB), 256, 0, stream>>>(head, U, Ahb);
    t2_kernel<<<512, 256, 0, stream>>>(head, dep, W, bias, t2h, t2d);
    biaffine_main<<<dim3(16, LL, BB), 256, 0, stream>>>(Ahb, depb, t2h, t2d, out);
}